// Round 3
// baseline (264.133 us; speedup 1.0000x reference)
//
#include <hip/hip_runtime.h>

#define B_  2
#define T_  2048
#define D_  1024
#define H_  16
#define DH_ 64
#define M_  4096   // B*T

typedef _Float16 f16;
typedef _Float16 f16x8 __attribute__((ext_vector_type(8)));
typedef _Float16 f16x4 __attribute__((ext_vector_type(4)));
typedef float    f32x4 __attribute__((ext_vector_type(4)));

__device__ __forceinline__ void async_ld16(const void* g, void* l) {
  __builtin_amdgcn_global_load_lds(
      (const __attribute__((address_space(1))) unsigned int*)g,
      (__attribute__((address_space(3))) unsigned int*)l,
      16, 0, 0);
}

// ---------------------------------------------------------------- convert ---
__global__ __launch_bounds__(256) void convert_all(
    const float* __restrict__ q, const float* __restrict__ k, const float* __restrict__ v,
    const float* __restrict__ wq, const float* __restrict__ wk, const float* __restrict__ wv,
    const float* __restrict__ wo, f16* __restrict__ xh, f16* __restrict__ wh) {
  int bid = blockIdx.x;
  const float* src;
  f16* dst;
  long base;
  if (bid < 6144) {                 // q,k,v : 3 x 4194304 elems, 2048 blocks each
    int r = bid >> 11;
    src = (r == 0) ? q : (r == 1) ? k : v;
    dst = xh + (long)r * 4194304;
    base = (long)(bid & 2047) * 2048;
  } else {                          // Wq,Wk,Wv,Wo : 4 x 1048576 elems, 512 blocks each
    int r = (bid - 6144) >> 9;
    src = (r == 0) ? wq : (r == 1) ? wk : (r == 2) ? wv : wo;
    dst = wh + (long)r * 1048576;
    base = (long)((bid - 6144) & 511) * 2048;
  }
  long e = base + (long)threadIdx.x * 8;
  const float4* s4 = (const float4*)(src + e);
  float4 f0 = s4[0], f1 = s4[1];
  f16x8 o;
  o[0] = (f16)f0.x; o[1] = (f16)f0.y; o[2] = (f16)f0.z; o[3] = (f16)f0.w;
  o[4] = (f16)f1.x; o[5] = (f16)f1.y; o[6] = (f16)f1.z; o[7] = (f16)f1.w;
  *(f16x8*)(dst + e) = o;
}

// ------------------------------------------------------------------- GEMM ---
// C = A(MxK) * W(NxK)^T.  M=4096, N=K=1024 for every GEMM in this problem.
// modes: 0 -> Qh (f16, *0.125)   1 -> Kh (f16)
//        2 -> Vt (f16, transposed per head [b,h,dh,t])   3 -> f32 out
__global__ __launch_bounds__(256) void gemm_k(
    const f16* __restrict__ Abase, const f16* __restrict__ Wbase,
    f16* __restrict__ Qb, f16* __restrict__ Kb, f16* __restrict__ Vt,
    float* __restrict__ Co, int which) {
  __shared__ __align__(16) f16 As[128][32];
  __shared__ __align__(16) f16 Bs[128][32];
  const int K = 1024, N = 1024;

  int mode;
  const f16 *A, *W;
  if (which) { mode = 3; A = Abase; W = Wbase; }
  else {
    mode = blockIdx.z;
    A = Abase + (long)blockIdx.z * 4194304;
    W = Wbase + (long)blockIdx.z * 1048576;
  }
  int m0 = blockIdx.y * 128, n0 = blockIdx.x * 128;
  int tid = threadIdx.x, lane = tid & 63, w = tid >> 6;
  int wm = w >> 1, wn = w & 1;

  const f16* pa = A + (long)(m0 + w * 16 + (lane >> 2)) * K + (lane & 3) * 8;
  const f16* pb = W + (long)(n0 + w * 16 + (lane >> 2)) * K + (lane & 3) * 8;
  f16* la = &As[w * 16 + (lane >> 2)][(lane & 3) * 8];
  f16* lb = &Bs[w * 16 + (lane >> 2)][(lane & 3) * 8];

  f32x4 acc[4][4] = {};
  int row = lane & 15, kq = (lane >> 4) * 8;

  for (int k0 = 0; k0 < K; k0 += 32) {
    async_ld16(pa + k0,          la);
    async_ld16(pa + 64 * K + k0, la + 64 * 32);
    async_ld16(pb + k0,          lb);
    async_ld16(pb + 64 * K + k0, lb + 64 * 32);
    __syncthreads();
    f16x8 af[4], bfr[4];
#pragma unroll
    for (int m = 0; m < 4; m++) af[m] = *(const f16x8*)&As[wm * 64 + m * 16 + row][kq];
#pragma unroll
    for (int n = 0; n < 4; n++) bfr[n] = *(const f16x8*)&Bs[wn * 64 + n * 16 + row][kq];
#pragma unroll
    for (int m = 0; m < 4; m++)
#pragma unroll
      for (int n = 0; n < 4; n++)
        acc[m][n] = __builtin_amdgcn_mfma_f32_16x16x32_f16(af[m], bfr[n], acc[m][n], 0, 0, 0);
    __syncthreads();
  }

  int r0 = (lane >> 4) * 4;
#pragma unroll
  for (int m = 0; m < 4; m++) {
    int gmb = m0 + wm * 64 + m * 16 + r0;
#pragma unroll
    for (int n = 0; n < 4; n++) {
      int gn = n0 + wn * 64 + n * 16 + row;
      if (mode == 0) {
#pragma unroll
        for (int i = 0; i < 4; i++)
          Qb[(long)(gmb + i) * N + gn] = (f16)(acc[m][n][i] * 0.125f);
      } else if (mode == 1) {
#pragma unroll
        for (int i = 0; i < 4; i++)
          Kb[(long)(gmb + i) * N + gn] = (f16)acc[m][n][i];
      } else if (mode == 2) {
        int b = gmb >> 11, t = gmb & 2047;
        int h = gn >> 6, dh = gn & 63;
        f16x4 pk;
#pragma unroll
        for (int i = 0; i < 4; i++) pk[i] = (f16)acc[m][n][i];
        *(f16x4*)&Vt[(long)((b * 16 + h) * 64 + dh) * 2048 + t] = pk;
      } else {
#pragma unroll
        for (int i = 0; i < 4; i++)
          Co[(long)(gmb + i) * N + gn] = acc[m][n][i];
      }
    }
  }
}

// -------------------------------------------------------------- attention ---
// grid (T/64, B*H), 256 threads. wave w owns q rows [qt*64 + w*16, +16).
__global__ __launch_bounds__(256) void attn_k(
    const f16* __restrict__ Q, const f16* __restrict__ Kp,
    const f16* __restrict__ Vt, const void* __restrict__ kpm_raw,
    f16* __restrict__ Ao) {
  __shared__ __align__(16) f16 Plds[4][16][64];
  __shared__ int s_cnt;
  int tid = threadIdx.x, lane = tid & 63, w = tid >> 6;
  int qt = blockIdx.x, bh = blockIdx.y;
  int b = bh >> 4, h = bh & 15;

  // ---- padding length. Harness passes bool as int32 ("integer -> const int*").
  // Detector: count zero BYTES of row b first (safe under both layouts). If the
  // data is really int32, that byte window covers only valid-region elements ->
  // count == 2048 exactly; true uint8 data gives len < 2048. Block-uniform.
  if (tid == 0) s_cnt = 0;
  __syncthreads();
  {
    const unsigned char* k8 = (const unsigned char*)kpm_raw;
    int cnt = 0;
    for (int j = tid; j < T_; j += 256) cnt += (k8[b * T_ + j] == 0) ? 1 : 0;
#pragma unroll
    for (int off = 1; off < 64; off <<= 1) cnt += __shfl_xor(cnt, off);
    if (lane == 0) atomicAdd(&s_cnt, cnt);
  }
  __syncthreads();
  int len = s_cnt;
  if (len == T_) {   // int32 bool layout -> recount on int elements
    __syncthreads();
    if (tid == 0) s_cnt = 0;
    __syncthreads();
    const int* k32 = (const int*)kpm_raw;
    int cnt = 0;
    for (int j = tid; j < T_; j += 256) cnt += (k32[b * T_ + j] == 0) ? 1 : 0;
#pragma unroll
    for (int off = 1; off < 64; off <<= 1) cnt += __shfl_xor(cnt, off);
    if (lane == 0) atomicAdd(&s_cnt, cnt);
    __syncthreads();
    len = s_cnt;
  }

  int q0 = qt * 64 + w * 16;
  const f16* Qh = Q  + (long)b * T_ * D_ + h * 64;
  const f16* Kh = Kp + (long)b * T_ * D_ + h * 64;
  const f16* Vh = Vt + (long)(b * 16 + h) * 64 * T_;

  int row = lane & 15, kq = (lane >> 4) * 8, r0 = (lane >> 4) * 4;

  f16x8 aq0 = *(const f16x8*)(Qh + (long)(q0 + row) * D_ + kq);
  f16x8 aq1 = *(const f16x8*)(Qh + (long)(q0 + row) * D_ + 32 + kq);

  f32x4 o[4] = {};
  float mrun[4], lrun[4];
#pragma unroll
  for (int i = 0; i < 4; i++) { mrun[i] = -1e30f; lrun[i] = 0.f; }

  int kmax = q0 + 16 < len ? q0 + 16 : len;   // exclusive bound on visible keys

  for (int kb = 0; kb < kmax; kb += 64) {
    f32x4 s[4] = {};
#pragma unroll
    for (int n = 0; n < 4; n++) {
      const f16* kp = Kh + (long)(kb + n * 16 + row) * D_ + kq;
      f16x8 b0 = *(const f16x8*)kp;
      f16x8 b1 = *(const f16x8*)(kp + 32);
      s[n] = __builtin_amdgcn_mfma_f32_16x16x32_f16(aq0, b0, s[n], 0, 0, 0);
      s[n] = __builtin_amdgcn_mfma_f32_16x16x32_f16(aq1, b1, s[n], 0, 0, 0);
    }
    float tmax[4];
#pragma unroll
    for (int i = 0; i < 4; i++) tmax[i] = -1e30f;
#pragma unroll
    for (int n = 0; n < 4; n++) {
      int gk = kb + n * 16 + row;
#pragma unroll
      for (int i = 0; i < 4; i++) {
        int gq = q0 + r0 + i;
        float vv = s[n][i];
        if (gk > gq || gk >= len) vv = -1e30f;
        s[n][i] = vv;
        tmax[i] = fmaxf(tmax[i], vv);
      }
    }
#pragma unroll
    for (int off = 1; off < 16; off <<= 1)
#pragma unroll
      for (int i = 0; i < 4; i++) tmax[i] = fmaxf(tmax[i], __shfl_xor(tmax[i], off));

    float sf[4], mnew[4];
#pragma unroll
    for (int i = 0; i < 4; i++) {
      mnew[i] = fmaxf(mrun[i], tmax[i]);
      sf[i] = __expf(mrun[i] - mnew[i]);
      mrun[i] = mnew[i];
      lrun[i] *= sf[i];
    }
#pragma unroll
    for (int n = 0; n < 4; n++)
#pragma unroll
      for (int i = 0; i < 4; i++) o[n][i] *= sf[i];

#pragma unroll
    for (int n = 0; n < 4; n++)
#pragma unroll
      for (int i = 0; i < 4; i++) {
        float p = __expf(s[n][i] - mnew[i]);
        f16 hp = (f16)p;
        lrun[i] += (float)hp;   // denominator from the SAME rounded weights PV uses
        Plds[w][r0 + i][n * 16 + row] = hp;
      }

    asm volatile("s_waitcnt lgkmcnt(0)" ::: "memory");
    __builtin_amdgcn_sched_barrier(0);

    f16x8 pa0 = *(const f16x8*)&Plds[w][row][kq];
    f16x8 pa1 = *(const f16x8*)&Plds[w][row][32 + kq];
#pragma unroll
    for (int n = 0; n < 4; n++) {
      const f16* vp = Vh + (long)(n * 16 + row) * T_ + kb + kq;
      f16x8 v0 = *(const f16x8*)vp;
      f16x8 v1 = *(const f16x8*)(vp + 32);
      o[n] = __builtin_amdgcn_mfma_f32_16x16x32_f16(pa0, v0, o[n], 0, 0, 0);
      o[n] = __builtin_amdgcn_mfma_f32_16x16x32_f16(pa1, v1, o[n], 0, 0, 0);
    }
  }

#pragma unroll
  for (int off = 1; off < 16; off <<= 1)
#pragma unroll
    for (int i = 0; i < 4; i++) lrun[i] += __shfl_xor(lrun[i], off);
  float linv[4];
#pragma unroll
  for (int i = 0; i < 4; i++) linv[i] = 1.f / lrun[i];

  f16* Aob = Ao + (long)(b * T_) * D_ + h * 64;
#pragma unroll
  for (int n = 0; n < 4; n++)
#pragma unroll
    for (int i = 0; i < 4; i++)
      Aob[(long)(q0 + r0 + i) * D_ + n * 16 + row] = (f16)(o[n][i] * linv[i]);
}

// ------------------------------------------------------------------ launch ---
extern "C" void kernel_launch(void* const* d_in, const int* in_sizes, int n_in,
                              void* d_out, int out_size, void* d_ws, size_t ws_size,
                              hipStream_t stream) {
  const float* q  = (const float*)d_in[0];
  const float* k  = (const float*)d_in[1];
  const float* v  = (const float*)d_in[2];
  // d_in[3] = causal mask (analytic, unused)
  const void* kpm = d_in[4];
  const float* wq = (const float*)d_in[5];
  const float* wk = (const float*)d_in[6];
  const float* wv = (const float*)d_in[7];
  const float* wo = (const float*)d_in[8];

  char* ws = (char*)d_ws;
  f16* Xh = (f16*)(ws);                     // 3 * 8 MB
  f16* Wh = (f16*)(ws + 25165824);          // 4 * 2 MB
  f16* Qb = (f16*)(ws + 33554432);          // 8 MB
  f16* Kb = (f16*)(ws + 41943040);          // 8 MB
  f16* Vt = (f16*)(ws + 50331648);          // 8 MB
  f16* Ao = (f16*)(ws + 58720256);          // 8 MB  (total 64 MB)

  convert_all<<<8192, 256, 0, stream>>>(q, k, v, wq, wk, wv, wo, Xh, Wh);

  gemm_k<<<dim3(8, 32, 3), 256, 0, stream>>>(Xh, Wh, Qb, Kb, Vt, nullptr, 0);

  attn_k<<<dim3(T_ / 64, B_ * H_), 256, 0, stream>>>(Qb, Kb, Vt, kpm, Ao);

  gemm_k<<<dim3(8, 32, 1), 256, 0, stream>>>(Ao, Wh + 3 * 1048576, nullptr, nullptr,
                                             nullptr, (float*)d_out, 1);
}

// Round 4
// 198.594 us; speedup vs baseline: 1.3300x; 1.3300x over previous
//
#include <hip/hip_runtime.h>

#define B_  2
#define T_  2048
#define D_  1024
#define H_  16
#define DH_ 64
#define M_  4096   // B*T

typedef _Float16 f16;
typedef _Float16 f16x8 __attribute__((ext_vector_type(8)));
typedef _Float16 f16x4 __attribute__((ext_vector_type(4)));
typedef float    f32x4  __attribute__((ext_vector_type(4)));
typedef float    f32x16 __attribute__((ext_vector_type(16)));
typedef unsigned int u32;

__device__ __forceinline__ void async_ld16(const void* g, void* l) {
  __builtin_amdgcn_global_load_lds(
      (const __attribute__((address_space(1))) unsigned int*)g,
      (__attribute__((address_space(3))) unsigned int*)l,
      16, 0, 0);
}

__device__ __forceinline__ u32 pkh(f16 a, f16 b) {
  union { f16 h[2]; u32 u; } x; x.h[0] = a; x.h[1] = b; return x.u;
}

// ---------------------------------------------------------------- convert ---
__global__ __launch_bounds__(256) void convert_all(
    const float* __restrict__ q, const float* __restrict__ k, const float* __restrict__ v,
    const float* __restrict__ wq, const float* __restrict__ wk, const float* __restrict__ wv,
    const float* __restrict__ wo, f16* __restrict__ xh, f16* __restrict__ wh) {
  int bid = blockIdx.x;
  const float* src;
  f16* dst;
  long base;
  if (bid < 6144) {                 // q,k,v : 3 x 4194304 elems, 2048 blocks each
    int r = bid >> 11;
    src = (r == 0) ? q : (r == 1) ? k : v;
    dst = xh + (long)r * 4194304;
    base = (long)(bid & 2047) * 2048;
  } else {                          // Wq,Wk,Wv,Wo : 4 x 1048576 elems, 512 blocks each
    int r = (bid - 6144) >> 9;
    src = (r == 0) ? wq : (r == 1) ? wk : (r == 2) ? wv : wo;
    dst = wh + (long)r * 1048576;
    base = (long)((bid - 6144) & 511) * 2048;
  }
  long e = base + (long)threadIdx.x * 8;
  const float4* s4 = (const float4*)(src + e);
  float4 f0 = s4[0], f1 = s4[1];
  f16x8 o;
  o[0] = (f16)f0.x; o[1] = (f16)f0.y; o[2] = (f16)f0.z; o[3] = (f16)f0.w;
  o[4] = (f16)f1.x; o[5] = (f16)f1.y; o[6] = (f16)f1.z; o[7] = (f16)f1.w;
  *(f16x8*)(dst + e) = o;
}

// ------------------------------------------------------------------- GEMM ---
// C = A(MxK) * W(NxK)^T.  M=4096, N=K=1024 for every GEMM in this problem.
// modes: 0 -> Qh (f16, *0.125)   1 -> Kh (f16)
//        2 -> Vt (f16, transposed per head [b,h,dh,t])   3 -> f32 out
__global__ __launch_bounds__(256) void gemm_k(
    const f16* __restrict__ Abase, const f16* __restrict__ Wbase,
    f16* __restrict__ Qb, f16* __restrict__ Kb, f16* __restrict__ Vt,
    float* __restrict__ Co, int which) {
  __shared__ __align__(16) f16 As[128][32];
  __shared__ __align__(16) f16 Bs[128][32];
  const int K = 1024, N = 1024;

  int mode;
  const f16 *A, *W;
  if (which) { mode = 3; A = Abase; W = Wbase; }
  else {
    mode = blockIdx.z;
    A = Abase + (long)blockIdx.z * 4194304;
    W = Wbase + (long)blockIdx.z * 1048576;
  }
  int m0 = blockIdx.y * 128, n0 = blockIdx.x * 128;
  int tid = threadIdx.x, lane = tid & 63, w = tid >> 6;
  int wm = w >> 1, wn = w & 1;

  const f16* pa = A + (long)(m0 + w * 16 + (lane >> 2)) * K + (lane & 3) * 8;
  const f16* pb = W + (long)(n0 + w * 16 + (lane >> 2)) * K + (lane & 3) * 8;
  f16* la = &As[w * 16 + (lane >> 2)][(lane & 3) * 8];
  f16* lb = &Bs[w * 16 + (lane >> 2)][(lane & 3) * 8];

  f32x4 acc[4][4] = {};
  int row = lane & 15, kq = (lane >> 4) * 8;

  for (int k0 = 0; k0 < K; k0 += 32) {
    async_ld16(pa + k0,          la);
    async_ld16(pa + 64 * K + k0, la + 64 * 32);
    async_ld16(pb + k0,          lb);
    async_ld16(pb + 64 * K + k0, lb + 64 * 32);
    __syncthreads();
    f16x8 af[4], bfr[4];
#pragma unroll
    for (int m = 0; m < 4; m++) af[m] = *(const f16x8*)&As[wm * 64 + m * 16 + row][kq];
#pragma unroll
    for (int n = 0; n < 4; n++) bfr[n] = *(const f16x8*)&Bs[wn * 64 + n * 16 + row][kq];
#pragma unroll
    for (int m = 0; m < 4; m++)
#pragma unroll
      for (int n = 0; n < 4; n++)
        acc[m][n] = __builtin_amdgcn_mfma_f32_16x16x32_f16(af[m], bfr[n], acc[m][n], 0, 0, 0);
    __syncthreads();
  }

  int r0 = (lane >> 4) * 4;
#pragma unroll
  for (int m = 0; m < 4; m++) {
    int gmb = m0 + wm * 64 + m * 16 + r0;
#pragma unroll
    for (int n = 0; n < 4; n++) {
      int gn = n0 + wn * 64 + n * 16 + row;
      if (mode == 0) {
#pragma unroll
        for (int i = 0; i < 4; i++)
          Qb[(long)(gmb + i) * N + gn] = (f16)(acc[m][n][i] * 0.125f);
      } else if (mode == 1) {
#pragma unroll
        for (int i = 0; i < 4; i++)
          Kb[(long)(gmb + i) * N + gn] = (f16)acc[m][n][i];
      } else if (mode == 2) {
        int b = gmb >> 11;
        int t = gmb & 2047;
        int h = gn >> 6, dh = gn & 63;
        f16x4 pk;
#pragma unroll
        for (int i = 0; i < 4; i++) pk[i] = (f16)acc[m][n][i];
        *(f16x4*)&Vt[(long)((b * 16 + h) * 64 + dh) * 2048 + t] = pk;
      } else {
#pragma unroll
        for (int i = 0; i < 4; i++)
          Co[(long)(gmb + i) * N + gn] = acc[m][n][i];
      }
    }
  }
}

// -------------------------------------------------------------- attention ---
// Swapped-operand 32x32x16 flash attention. 1 wave per block, 32 q-rows/wave.
// grid (T/32, B*H), 64 threads. Lane owns q = q0+(lane&31); hi = lane>>5 picks
// the k/dh slice. S = mfma(Kfrag, Qfrag) -> lane holds 16 k-scores of one q.
struct KVt {
  f16x8 kf[4];   // K rows kb..kb+31, dh slices 16t + hi*8
  f16x8 vf[4];   // V^T: [d*2+m] = dh-tile d rows, k-slice kb+16m+hi*8
};

__global__ __launch_bounds__(64) void attn_k(
    const f16* __restrict__ Q, const f16* __restrict__ Kp,
    const f16* __restrict__ Vt, const void* __restrict__ kpm_raw,
    f16* __restrict__ Ao) {
  int lane = threadIdx.x;
  int qt = blockIdx.x, bh = blockIdx.y;
  int b = bh >> 4, h = bh & 15;
  int r31 = lane & 31, hi = lane >> 5, hi8 = hi * 8;

  // ---- padding length (bool passed as int32; dual-layout detector, wave-level)
  int len;
  {
    const unsigned char* k8 = (const unsigned char*)kpm_raw + (long)b * T_;
    int cnt = 0;
    for (int j = lane; j < T_; j += 64) cnt += (k8[j] == 0) ? 1 : 0;
#pragma unroll
    for (int off = 1; off < 64; off <<= 1) cnt += __shfl_xor(cnt, off);
    len = cnt;
    if (len == T_) {
      const int* k32 = (const int*)kpm_raw + (long)b * T_;
      cnt = 0;
      for (int j = lane; j < T_; j += 64) cnt += (k32[j] == 0) ? 1 : 0;
#pragma unroll
      for (int off = 1; off < 64; off <<= 1) cnt += __shfl_xor(cnt, off);
      len = cnt;
    }
  }

  int q0 = qt * 32;
  int gq = q0 + r31;
  const f16* Qh = Q  + (long)b * T_ * D_ + h * 64;
  const f16* Kh = Kp + (long)b * T_ * D_ + h * 64;
  const f16* Vh = Vt + (long)(b * 16 + h) * 64 * T_;

  // Q fragments (B-operand): lane holds Q[q0+r31][16t + hi*8 + j]
  f16x8 qf[4];
#pragma unroll
  for (int t = 0; t < 4; t++)
    qf[t] = *(const f16x8*)(Qh + (long)gq * D_ + t * 16 + hi8);

  f32x16 o0 = {}, o1 = {};       // O^T: dh-tiles 0 (0..31) and 1 (32..63)
  float mrun = -1e30f, lrun = 0.f;

  int kmax = (q0 + 32 < len) ? q0 + 32 : len;

  KVt bufA, bufB;

  auto LOADKV = [&](KVt& t, int kb) {
    const f16* kp = Kh + ((long)kb + r31) * D_ + hi8;
    t.kf[0] = *(const f16x8*)(kp);
    t.kf[1] = *(const f16x8*)(kp + 16);
    t.kf[2] = *(const f16x8*)(kp + 32);
    t.kf[3] = *(const f16x8*)(kp + 48);
    const f16* vp = Vh + (long)r31 * T_ + kb + hi8;
    t.vf[0] = *(const f16x8*)(vp);
    t.vf[1] = *(const f16x8*)(vp + 16);
    t.vf[2] = *(const f16x8*)(vp + 32 * T_);
    t.vf[3] = *(const f16x8*)(vp + 32 * T_ + 16);
  };

  auto PROC = [&](KVt& t, int kb) {
    f32x16 s = {};
#pragma unroll
    for (int tt = 0; tt < 4; tt++)
      s = __builtin_amdgcn_mfma_f32_32x32x16_f16(t.kf[tt], qf[tt], s, 0, 0, 0);

    bool needmask = (kb + 32 > q0) || (kb + 32 > len);
    float sv[16];
    if (needmask) {
#pragma unroll
      for (int r = 0; r < 16; r++) {
        int gk = kb + (r & 3) + 8 * (r >> 2) + 4 * hi;
        sv[r] = (gk > gq || gk >= len) ? -1e30f : s[r];
      }
    } else {
#pragma unroll
      for (int r = 0; r < 16; r++) sv[r] = s[r];
    }

    // row max: in-lane tree over 16, then one half-exchange
    float mx01 = fmaxf(fmaxf(sv[0], sv[1]), fmaxf(sv[2], sv[3]));
    float mx23 = fmaxf(fmaxf(sv[4], sv[5]), fmaxf(sv[6], sv[7]));
    float mx45 = fmaxf(fmaxf(sv[8], sv[9]), fmaxf(sv[10], sv[11]));
    float mx67 = fmaxf(fmaxf(sv[12], sv[13]), fmaxf(sv[14], sv[15]));
    float mx = fmaxf(fmaxf(mx01, mx23), fmaxf(mx45, mx67));
    mx = fmaxf(mx, __shfl_xor(mx, 32));

    float mnew = fmaxf(mrun, mx);
    float sf = __expf(mrun - mnew);
    mrun = mnew;

    f16 p16[16];
    float ps[4] = {0.f, 0.f, 0.f, 0.f};
#pragma unroll
    for (int r = 0; r < 16; r++) {
      float p = __expf(sv[r] - mnew);
      f16 hp = (f16)p;
      p16[r] = hp;
      ps[r & 3] += (float)hp;    // denominator from the SAME rounded weights
    }
    float psum = (ps[0] + ps[1]) + (ps[2] + ps[3]);
    lrun = lrun * sf + psum + __shfl_xor(psum, 32);

    o0 *= sf;
    o1 *= sf;

    // build PV B-operand fragments via pack + half-exchange + select
    u32 A0 = pkh(p16[0],  p16[1]),  A1 = pkh(p16[2],  p16[3]);
    u32 B0 = pkh(p16[4],  p16[5]),  B1 = pkh(p16[6],  p16[7]);
    u32 C0 = pkh(p16[8],  p16[9]),  C1 = pkh(p16[10], p16[11]);
    u32 D0 = pkh(p16[12], p16[13]), D1 = pkh(p16[14], p16[15]);
    u32 sA0 = __shfl_xor(A0, 32), sA1 = __shfl_xor(A1, 32);
    u32 sB0 = __shfl_xor(B0, 32), sB1 = __shfl_xor(B1, 32);
    u32 sC0 = __shfl_xor(C0, 32), sC1 = __shfl_xor(C1, 32);
    u32 sD0 = __shfl_xor(D0, 32), sD1 = __shfl_xor(D1, 32);

    union { u32 w[4]; f16x8 v; } f0, f1;
    f0.w[0] = hi ? sB0 : A0;  f0.w[1] = hi ? sB1 : A1;
    f0.w[2] = hi ? B0 : sA0;  f0.w[3] = hi ? B1 : sA1;
    f1.w[0] = hi ? sD0 : C0;  f1.w[1] = hi ? sD1 : C1;
    f1.w[2] = hi ? D0 : sC0;  f1.w[3] = hi ? D1 : sC1;

    o0 = __builtin_amdgcn_mfma_f32_32x32x16_f16(t.vf[0], f0.v, o0, 0, 0, 0);
    o0 = __builtin_amdgcn_mfma_f32_32x32x16_f16(t.vf[1], f1.v, o0, 0, 0, 0);
    o1 = __builtin_amdgcn_mfma_f32_32x32x16_f16(t.vf[2], f0.v, o1, 0, 0, 0);
    o1 = __builtin_amdgcn_mfma_f32_32x32x16_f16(t.vf[3], f1.v, o1, 0, 0, 0);
  };

  // software-pipelined ping-pong over k-tiles of 32
  LOADKV(bufA, 0);
  int kb = 0;
  while (true) {
    if (kb + 32 < kmax) LOADKV(bufB, kb + 32);
    PROC(bufA, kb);
    kb += 32;
    if (kb >= kmax) break;
    if (kb + 32 < kmax) LOADKV(bufA, kb + 32);
    PROC(bufB, kb);
    kb += 32;
    if (kb >= kmax) break;
  }

  float linv = 1.f / lrun;
  f16* Aob = Ao + (long)(b * T_ + gq) * D_ + h * 64 + 4 * hi;
#pragma unroll
  for (int g = 0; g < 4; g++) {
    f16x4 s0, s1;
#pragma unroll
    for (int i = 0; i < 4; i++) {
      s0[i] = (f16)(o0[g * 4 + i] * linv);
      s1[i] = (f16)(o1[g * 4 + i] * linv);
    }
    *(f16x4*)(Aob + 8 * g)      = s0;
    *(f16x4*)(Aob + 32 + 8 * g) = s1;
  }
}

// ------------------------------------------------------------------ launch ---
extern "C" void kernel_launch(void* const* d_in, const int* in_sizes, int n_in,
                              void* d_out, int out_size, void* d_ws, size_t ws_size,
                              hipStream_t stream) {
  const float* q  = (const float*)d_in[0];
  const float* k  = (const float*)d_in[1];
  const float* v  = (const float*)d_in[2];
  // d_in[3] = causal mask (analytic, unused)
  const void* kpm = d_in[4];
  const float* wq = (const float*)d_in[5];
  const float* wk = (const float*)d_in[6];
  const float* wv = (const float*)d_in[7];
  const float* wo = (const float*)d_in[8];

  char* ws = (char*)d_ws;
  f16* Xh = (f16*)(ws);                     // 3 * 8 MB
  f16* Wh = (f16*)(ws + 25165824);          // 4 * 2 MB
  f16* Qb = (f16*)(ws + 33554432);          // 8 MB
  f16* Kb = (f16*)(ws + 41943040);          // 8 MB
  f16* Vt = (f16*)(ws + 50331648);          // 8 MB
  f16* Ao = (f16*)(ws + 58720256);          // 8 MB  (total 64 MB)

  convert_all<<<8192, 256, 0, stream>>>(q, k, v, wq, wk, wv, wo, Xh, Wh);

  gemm_k<<<dim3(8, 32, 3), 256, 0, stream>>>(Xh, Wh, Qb, Kb, Vt, nullptr, 0);

  attn_k<<<dim3(T_ / 32, B_ * H_), 64, 0, stream>>>(Qb, Kb, Vt, kpm, Ao);

  gemm_k<<<dim3(8, 32, 1), 256, 0, stream>>>(Ao, Wh + 3 * 1048576, nullptr, nullptr,
                                             nullptr, (float*)d_out, 1);
}

// Round 5
// 188.630 us; speedup vs baseline: 1.4003x; 1.0528x over previous
//
#include <hip/hip_runtime.h>

#define B_  2
#define T_  2048
#define D_  1024
#define H_  16
#define DH_ 64
#define M_  4096   // B*T

typedef _Float16 f16;
typedef _Float16 f16x8 __attribute__((ext_vector_type(8)));
typedef _Float16 f16x4 __attribute__((ext_vector_type(4)));
typedef float    f32x4  __attribute__((ext_vector_type(4)));
typedef float    f32x16 __attribute__((ext_vector_type(16)));
typedef unsigned int u32;

__device__ __forceinline__ void async_ld16(const void* g, void* l) {
  __builtin_amdgcn_global_load_lds(
      (const __attribute__((address_space(1))) unsigned int*)g,
      (__attribute__((address_space(3))) unsigned int*)l,
      16, 0, 0);
}

__device__ __forceinline__ u32 pkh(f16 a, f16 b) {
  union { f16 h[2]; u32 u; } x; x.h[0] = a; x.h[1] = b; return x.u;
}

// ---------------------------------------------------------------- convert ---
// blocks 0..8191: f32->f16 conversion.  blocks 8192..8193: per-batch padding
// length (dual-layout bool detector), written to lens_out[b].
__global__ __launch_bounds__(256) void convert_all(
    const float* __restrict__ q, const float* __restrict__ k, const float* __restrict__ v,
    const float* __restrict__ wq, const float* __restrict__ wk, const float* __restrict__ wv,
    const float* __restrict__ wo, const void* __restrict__ kpm_raw,
    f16* __restrict__ xh, f16* __restrict__ wh, int* __restrict__ lens_out) {
  int bid = blockIdx.x;
  if (bid >= 8192) {                // padding length for batch b
    int b = bid - 8192;
    __shared__ int s_c8, s_c32;
    if (threadIdx.x == 0) { s_c8 = 0; s_c32 = 0; }
    __syncthreads();
    int tid = threadIdx.x, lane = tid & 63;
    {
      const unsigned char* k8 = (const unsigned char*)kpm_raw + (long)b * T_;
      int cnt = 0;
      for (int j = tid; j < T_; j += 256) cnt += (k8[j] == 0) ? 1 : 0;
#pragma unroll
      for (int off = 1; off < 64; off <<= 1) cnt += __shfl_xor(cnt, off);
      if (lane == 0) atomicAdd(&s_c8, cnt);
    }
    {
      const int* k32 = (const int*)kpm_raw + (long)b * T_;
      int cnt = 0;
      for (int j = tid; j < T_; j += 256) cnt += (k32[j] == 0) ? 1 : 0;
#pragma unroll
      for (int off = 1; off < 64; off <<= 1) cnt += __shfl_xor(cnt, off);
      if (lane == 0) atomicAdd(&s_c32, cnt);
    }
    __syncthreads();
    if (tid == 0) lens_out[b] = (s_c8 == T_) ? s_c32 : s_c8;
    return;
  }
  const float* src;
  f16* dst;
  long base;
  if (bid < 6144) {                 // q,k,v : 3 x 4194304 elems, 2048 blocks each
    int r = bid >> 11;
    src = (r == 0) ? q : (r == 1) ? k : v;
    dst = xh + (long)r * 4194304;
    base = (long)(bid & 2047) * 2048;
  } else {                          // Wq,Wk,Wv,Wo : 4 x 1048576 elems, 512 blocks each
    int r = (bid - 6144) >> 9;
    src = (r == 0) ? wq : (r == 1) ? wk : (r == 2) ? wv : wo;
    dst = wh + (long)r * 1048576;
    base = (long)((bid - 6144) & 511) * 2048;
  }
  long e = base + (long)threadIdx.x * 8;
  const float4* s4 = (const float4*)(src + e);
  float4 f0 = s4[0], f1 = s4[1];
  f16x8 o;
  o[0] = (f16)f0.x; o[1] = (f16)f0.y; o[2] = (f16)f0.z; o[3] = (f16)f0.w;
  o[4] = (f16)f1.x; o[5] = (f16)f1.y; o[6] = (f16)f1.z; o[7] = (f16)f1.w;
  *(f16x8*)(dst + e) = o;
}

// ------------------------------------------------------------------- GEMM ---
// C = A(MxK) * W(NxK)^T.  M=4096, N=K=1024 for every GEMM in this problem.
// modes: 0 -> Qh (f16, *0.125)   1 -> Kh (f16)
//        2 -> Vt (f16, transposed per head [b,h,dh,t])   3 -> f32 out
__global__ __launch_bounds__(256) void gemm_k(
    const f16* __restrict__ Abase, const f16* __restrict__ Wbase,
    f16* __restrict__ Qb, f16* __restrict__ Kb, f16* __restrict__ Vt,
    float* __restrict__ Co, int which) {
  __shared__ __align__(16) f16 As[128][32];
  __shared__ __align__(16) f16 Bs[128][32];
  const int K = 1024, N = 1024;

  int mode;
  const f16 *A, *W;
  if (which) { mode = 3; A = Abase; W = Wbase; }
  else {
    mode = blockIdx.z;
    A = Abase + (long)blockIdx.z * 4194304;
    W = Wbase + (long)blockIdx.z * 1048576;
  }
  int m0 = blockIdx.y * 128, n0 = blockIdx.x * 128;
  int tid = threadIdx.x, lane = tid & 63, w = tid >> 6;
  int wm = w >> 1, wn = w & 1;

  const f16* pa = A + (long)(m0 + w * 16 + (lane >> 2)) * K + (lane & 3) * 8;
  const f16* pb = W + (long)(n0 + w * 16 + (lane >> 2)) * K + (lane & 3) * 8;
  f16* la = &As[w * 16 + (lane >> 2)][(lane & 3) * 8];
  f16* lb = &Bs[w * 16 + (lane >> 2)][(lane & 3) * 8];

  f32x4 acc[4][4] = {};
  int row = lane & 15, kq = (lane >> 4) * 8;

  for (int k0 = 0; k0 < K; k0 += 32) {
    async_ld16(pa + k0,          la);
    async_ld16(pa + 64 * K + k0, la + 64 * 32);
    async_ld16(pb + k0,          lb);
    async_ld16(pb + 64 * K + k0, lb + 64 * 32);
    __syncthreads();
    f16x8 af[4], bfr[4];
#pragma unroll
    for (int m = 0; m < 4; m++) af[m] = *(const f16x8*)&As[wm * 64 + m * 16 + row][kq];
#pragma unroll
    for (int n = 0; n < 4; n++) bfr[n] = *(const f16x8*)&Bs[wn * 64 + n * 16 + row][kq];
#pragma unroll
    for (int m = 0; m < 4; m++)
#pragma unroll
      for (int n = 0; n < 4; n++)
        acc[m][n] = __builtin_amdgcn_mfma_f32_16x16x32_f16(af[m], bfr[n], acc[m][n], 0, 0, 0);
    __syncthreads();
  }

  int r0 = (lane >> 4) * 4;
#pragma unroll
  for (int m = 0; m < 4; m++) {
    int gmb = m0 + wm * 64 + m * 16 + r0;
#pragma unroll
    for (int n = 0; n < 4; n++) {
      int gn = n0 + wn * 64 + n * 16 + row;
      if (mode == 0) {
#pragma unroll
        for (int i = 0; i < 4; i++)
          Qb[(long)(gmb + i) * N + gn] = (f16)(acc[m][n][i] * 0.125f);
      } else if (mode == 1) {
#pragma unroll
        for (int i = 0; i < 4; i++)
          Kb[(long)(gmb + i) * N + gn] = (f16)acc[m][n][i];
      } else if (mode == 2) {
        int b = gmb >> 11;
        int t = gmb & 2047;
        int h = gn >> 6, dh = gn & 63;
        f16x4 pk;
#pragma unroll
        for (int i = 0; i < 4; i++) pk[i] = (f16)acc[m][n][i];
        *(f16x4*)&Vt[(long)((b * 16 + h) * 64 + dh) * 2048 + t] = pk;
      } else {
#pragma unroll
        for (int i = 0; i < 4; i++)
          Co[(long)(gmb + i) * N + gn] = acc[m][n][i];
      }
    }
  }
}

// -------------------------------------------------------------- attention ---
// Swapped-operand 32x32x16 flash attention, KVBLK=64 (two 32-k S-tiles with a
// single joint online-softmax update). 1 wave/block, 32 q-rows/wave.
struct KV64 {
  f16x8 kf[8];   // [tile(2)][dh-slice(4)]
  f16x8 vf[8];   // [dh-tile(2)][k-slice(4)]
};

__global__ __launch_bounds__(64) void attn_k(
    const f16* __restrict__ Q, const f16* __restrict__ Kp,
    const f16* __restrict__ Vt, const int* __restrict__ Lens,
    f16* __restrict__ Ao) {
  int lane = threadIdx.x;
  int qt = (gridDim.x - 1) - blockIdx.x;   // longest-first
  int bh = blockIdx.y;
  int b = bh >> 4, h = bh & 15;
  int r31 = lane & 31, hi = lane >> 5, hi8 = hi * 8;

  int len = Lens[b];

  int q0 = qt * 32;
  int gq = q0 + r31;
  const f16* Qh = Q  + (long)b * T_ * D_ + h * 64;
  const f16* Kh = Kp + (long)b * T_ * D_ + h * 64;
  const f16* Vh = Vt + (long)(b * 16 + h) * 64 * T_;

  f16x8 qf[4];
#pragma unroll
  for (int t = 0; t < 4; t++)
    qf[t] = *(const f16x8*)(Qh + (long)gq * D_ + t * 16 + hi8);

  f32x16 o0 = {}, o1 = {};       // O^T: dh-tiles 0 (0..31) and 1 (32..63)
  float mrun = -1e30f, lrun = 0.f;

  int kmax = (q0 + 32 < len) ? q0 + 32 : len;   // exclusive bound on visible keys

  KV64 bufA, bufB;

  auto LOADKV = [&](KV64& t, int kb) {
    const f16* kp = Kh + ((long)kb + r31) * D_ + hi8;
#pragma unroll
    for (int tt = 0; tt < 2; tt++)
#pragma unroll
      for (int tq = 0; tq < 4; tq++)
        t.kf[tt * 4 + tq] = *(const f16x8*)(kp + tt * 32 * D_ + tq * 16);
    const f16* vp = Vh + (long)r31 * T_ + kb + hi8;
#pragma unroll
    for (int d = 0; d < 2; d++)
#pragma unroll
      for (int m = 0; m < 4; m++)
        t.vf[d * 4 + m] = *(const f16x8*)(vp + d * 32 * T_ + m * 16);
  };

  auto PROC = [&](KV64& t, int kb) {
    f32x16 s0 = {}, s1 = {};
#pragma unroll
    for (int tq = 0; tq < 4; tq++) {
      s0 = __builtin_amdgcn_mfma_f32_32x32x16_f16(t.kf[tq],     qf[tq], s0, 0, 0, 0);
      s1 = __builtin_amdgcn_mfma_f32_32x32x16_f16(t.kf[4 + tq], qf[tq], s1, 0, 0, 0);
    }

    bool needmask = (kb + 64 > q0) || (kb + 64 > len);
    float sv[32];
    if (needmask) {
#pragma unroll
      for (int r = 0; r < 16; r++) {
        int pat = (r & 3) + 8 * (r >> 2) + 4 * hi;
        int gk0 = kb + pat, gk1 = kb + 32 + pat;
        sv[r]      = (gk0 > gq || gk0 >= len) ? -1e30f : s0[r];
        sv[16 + r] = (gk1 > gq || gk1 >= len) ? -1e30f : s1[r];
      }
    } else {
#pragma unroll
      for (int r = 0; r < 16; r++) { sv[r] = s0[r]; sv[16 + r] = s1[r]; }
    }

    // joint row max over 32 values + one half-exchange
    float mx = fmaxf(sv[0], sv[1]);
#pragma unroll
    for (int r = 2; r < 32; r++) mx = fmaxf(mx, sv[r]);
    mx = fmaxf(mx, __shfl_xor(mx, 32));

    float mnew = fmaxf(mrun, mx);
    float sf = __expf(mrun - mnew);
    mrun = mnew;

    f16 p16[32];
    float ps[4] = {0.f, 0.f, 0.f, 0.f};
#pragma unroll
    for (int r = 0; r < 32; r++) {
      float p = __expf(sv[r] - mnew);
      f16 hp = (f16)p;
      p16[r] = hp;
      ps[r & 3] += (float)hp;    // denominator from the SAME rounded weights
    }
    float psum = (ps[0] + ps[1]) + (ps[2] + ps[3]);
    lrun = lrun * sf + psum + __shfl_xor(psum, 32);

    o0 *= sf;
    o1 *= sf;

    // pack + half-exchange + select -> PV B-operand fragments (per 32-k tile)
    u32 A0 = pkh(p16[0],  p16[1]),  A1 = pkh(p16[2],  p16[3]);
    u32 B0 = pkh(p16[4],  p16[5]),  B1 = pkh(p16[6],  p16[7]);
    u32 C0 = pkh(p16[8],  p16[9]),  C1 = pkh(p16[10], p16[11]);
    u32 D0 = pkh(p16[12], p16[13]), D1 = pkh(p16[14], p16[15]);
    u32 E0 = pkh(p16[16], p16[17]), E1 = pkh(p16[18], p16[19]);
    u32 F0 = pkh(p16[20], p16[21]), F1 = pkh(p16[22], p16[23]);
    u32 G0 = pkh(p16[24], p16[25]), G1 = pkh(p16[26], p16[27]);
    u32 H0 = pkh(p16[28], p16[29]), H1 = pkh(p16[30], p16[31]);
    u32 sA0 = __shfl_xor(A0, 32), sA1 = __shfl_xor(A1, 32);
    u32 sB0 = __shfl_xor(B0, 32), sB1 = __shfl_xor(B1, 32);
    u32 sC0 = __shfl_xor(C0, 32), sC1 = __shfl_xor(C1, 32);
    u32 sD0 = __shfl_xor(D0, 32), sD1 = __shfl_xor(D1, 32);
    u32 sE0 = __shfl_xor(E0, 32), sE1 = __shfl_xor(E1, 32);
    u32 sF0 = __shfl_xor(F0, 32), sF1 = __shfl_xor(F1, 32);
    u32 sG0 = __shfl_xor(G0, 32), sG1 = __shfl_xor(G1, 32);
    u32 sH0 = __shfl_xor(H0, 32), sH1 = __shfl_xor(H1, 32);

    union { u32 w[4]; f16x8 v; } f00, f01, f10, f11;
    f00.w[0] = hi ? sB0 : A0;  f00.w[1] = hi ? sB1 : A1;
    f00.w[2] = hi ? B0 : sA0;  f00.w[3] = hi ? B1 : sA1;
    f01.w[0] = hi ? sD0 : C0;  f01.w[1] = hi ? sD1 : C1;
    f01.w[2] = hi ? D0 : sC0;  f01.w[3] = hi ? D1 : sC1;
    f10.w[0] = hi ? sF0 : E0;  f10.w[1] = hi ? sF1 : E1;
    f10.w[2] = hi ? F0 : sE0;  f10.w[3] = hi ? F1 : sE1;
    f11.w[0] = hi ? sH0 : G0;  f11.w[1] = hi ? sH1 : G1;
    f11.w[2] = hi ? H0 : sG0;  f11.w[3] = hi ? H1 : sG1;

    o0 = __builtin_amdgcn_mfma_f32_32x32x16_f16(t.vf[0], f00.v, o0, 0, 0, 0);
    o0 = __builtin_amdgcn_mfma_f32_32x32x16_f16(t.vf[1], f01.v, o0, 0, 0, 0);
    o0 = __builtin_amdgcn_mfma_f32_32x32x16_f16(t.vf[2], f10.v, o0, 0, 0, 0);
    o0 = __builtin_amdgcn_mfma_f32_32x32x16_f16(t.vf[3], f11.v, o0, 0, 0, 0);
    o1 = __builtin_amdgcn_mfma_f32_32x32x16_f16(t.vf[4], f00.v, o1, 0, 0, 0);
    o1 = __builtin_amdgcn_mfma_f32_32x32x16_f16(t.vf[5], f01.v, o1, 0, 0, 0);
    o1 = __builtin_amdgcn_mfma_f32_32x32x16_f16(t.vf[6], f10.v, o1, 0, 0, 0);
    o1 = __builtin_amdgcn_mfma_f32_32x32x16_f16(t.vf[7], f11.v, o1, 0, 0, 0);
  };

  // software-pipelined ping-pong over 64-wide k-tiles
  LOADKV(bufA, 0);
  int kb = 0;
  while (true) {
    if (kb + 64 < kmax) LOADKV(bufB, kb + 64);
    PROC(bufA, kb);
    kb += 64;
    if (kb >= kmax) break;
    if (kb + 64 < kmax) LOADKV(bufA, kb + 64);
    PROC(bufB, kb);
    kb += 64;
    if (kb >= kmax) break;
  }

  float linv = 1.f / lrun;
  f16* Aob = Ao + (long)(b * T_ + gq) * D_ + h * 64 + 4 * hi;
#pragma unroll
  for (int g = 0; g < 4; g++) {
    f16x4 s0, s1;
#pragma unroll
    for (int i = 0; i < 4; i++) {
      s0[i] = (f16)(o0[g * 4 + i] * linv);
      s1[i] = (f16)(o1[g * 4 + i] * linv);
    }
    *(f16x4*)(Aob + 8 * g)      = s0;
    *(f16x4*)(Aob + 32 + 8 * g) = s1;
  }
}

// ------------------------------------------------------------------ launch ---
extern "C" void kernel_launch(void* const* d_in, const int* in_sizes, int n_in,
                              void* d_out, int out_size, void* d_ws, size_t ws_size,
                              hipStream_t stream) {
  const float* q  = (const float*)d_in[0];
  const float* k  = (const float*)d_in[1];
  const float* v  = (const float*)d_in[2];
  // d_in[3] = causal mask (analytic, unused)
  const void* kpm = d_in[4];
  const float* wq = (const float*)d_in[5];
  const float* wk = (const float*)d_in[6];
  const float* wv = (const float*)d_in[7];
  const float* wo = (const float*)d_in[8];

  char* ws = (char*)d_ws;
  f16* Xh = (f16*)(ws);                     // 3 * 8 MB
  f16* Wh = (f16*)(ws + 25165824);          // 4 * 2 MB
  f16* Qb = (f16*)(ws + 33554432);          // 8 MB
  f16* Kb = (f16*)(ws + 41943040);          // 8 MB
  f16* Vt = (f16*)(ws + 50331648);          // 8 MB
  f16* Ao = (f16*)(ws + 58720256);          // 8 MB  (total 64 MB)
  // Lens scratch: first 2 ints of d_out — fully overwritten by the final GEMM
  // (which runs after attn reads them), so the output is still correct.
  int* Lens = (int*)d_out;

  convert_all<<<8194, 256, 0, stream>>>(q, k, v, wq, wk, wv, wo, kpm, Xh, Wh, Lens);

  gemm_k<<<dim3(8, 32, 3), 256, 0, stream>>>(Xh, Wh, Qb, Kb, Vt, nullptr, 0);

  attn_k<<<dim3(T_ / 32, B_ * H_), 64, 0, stream>>>(Qb, Kb, Vt, Lens, Ao);

  gemm_k<<<dim3(8, 32, 1), 256, 0, stream>>>(Ao, Wh + 3 * 1048576, nullptr, nullptr,
                                             nullptr, (float*)d_out, 1);
}